// Round 5
// baseline (49453.296 us; speedup 1.0000x reference)
//
#include <hip/hip_runtime.h>
#include <math.h>

constexpr int kB  = 128;
constexpr int kT  = 1024;
constexpr int kD  = 32;
constexpr int kH  = 64;
constexpr int kW  = 128;
constexpr int kC  = kD + 1;    // 33
constexpr int kO  = kH * kC;   // 2112
constexpr int kIN = kH + 1;    // 65
constexpr int BLOCK = 1024;    // 16 waves

// ---- int16 workspace layout (u32 units) ----
// W2: transposed tiles: uint4 index (R*16+q)*64 + r ; R=row>>6, r=row&63, q=0..15
constexpr int WS_W2  = 0;            // 135168 u32 (2112 rows * 64 words)
constexpr int WS_W1  = 135168;       // 8192 u32  (128 rows * 64 words, row-major)
constexpr int WS_W0  = 143360;       // 4224 u32  (128 rows * 33 words, 65 cols + pad)
constexpr int WS_SC2 = 147584;       // 2112 f32 row scales
constexpr int WS_SC1 = 149696;       // 128
constexpr int WS_SC0 = 149824;       // 128
constexpr int WS_TOT = 149952;       // u32 -> 599,808 bytes

__device__ __forceinline__ float fast_sigmoid(float x) { return 1.0f / (1.0f + __expf(-x)); }
__device__ __forceinline__ float lipswish_f(float x)   { return 0.909f * x * fast_sigmoid(x); }
__device__ __forceinline__ float fast_tanh(float x) {
    float ax = fabsf(x);
    float e  = __expf(2.0f * ax);
    float r  = 1.0f - 2.0f / (e + 1.0f);
    return copysignf(r, x);
}
__device__ __forceinline__ float dot4(float4 a, float4 b) {
    return a.x * b.x + a.y * b.y + a.z * b.z + a.w * b.w;
}
// acc += dot(int16 pair in u, z0, z1)
__device__ __forceinline__ float fma2i(unsigned u, float z0, float z1, float acc) {
    int lo = (int)(short)(u & 0xffffu);
    int hi = ((int)u) >> 16;
    acc += (float)lo * z0 + (float)hi * z1;
    return acc;
}
__device__ __forceinline__ float fma8i(uint4 u, float4 zl, float4 zh, float acc) {
    acc = fma2i(u.x, zl.x, zl.y, acc);
    acc = fma2i(u.y, zl.z, zl.w, acc);
    acc = fma2i(u.z, zh.x, zh.y, acc);
    acc = fma2i(u.w, zh.z, zh.w, acc);
    return acc;
}
__device__ __forceinline__ int q15(float w, float inv) {
    float q = rintf(w * inv);
    q = fmaxf(-32767.0f, fminf(32767.0f, q));
    return (int)q;
}
__device__ __forceinline__ unsigned pack16(int a, int b) {
    return ((unsigned)a & 0xffffu) | ((unsigned)b << 16);
}

// one wave (64 threads) per row; rows: [0,2112) W2, [2112,2240) W1, [2240,2368) W0
__global__ __launch_bounds__(64)
void prep_kernel(const float* __restrict__ vW0, const float* __restrict__ vW1,
                 const float* __restrict__ vW2, unsigned* __restrict__ ws)
{
    const int row  = blockIdx.x;
    const int lane = threadIdx.x;
    float* scf = (float*)ws;

    if (row < kO) {                                   // vW2 row, 128 cols
        const float* src = vW2 + (size_t)row * kW;
        float m = fmaxf(fabsf(src[lane]), fabsf(src[lane + 64]));
        #pragma unroll
        for (int s = 1; s < 64; s <<= 1) m = fmaxf(m, __shfl_xor(m, s));
        float inv = (m > 0.0f) ? 32767.0f / m : 0.0f;
        if (lane == 0) scf[WS_SC2 + row] = (m > 0.0f) ? m / 32767.0f : 0.0f;
        int w = lane;
        unsigned pk = pack16(q15(src[2 * w], inv), q15(src[2 * w + 1], inv));
        int R = row >> 6, r = row & 63, q = w >> 2, e = w & 3;
        ws[WS_W2 + (((R * 16 + q) * 64 + r) << 2) + e] = pk;
    } else if (row < kO + kW) {                       // vW1 row, 128 cols
        int r = row - kO;
        const float* src = vW1 + (size_t)r * kW;
        float m = fmaxf(fabsf(src[lane]), fabsf(src[lane + 64]));
        #pragma unroll
        for (int s = 1; s < 64; s <<= 1) m = fmaxf(m, __shfl_xor(m, s));
        float inv = (m > 0.0f) ? 32767.0f / m : 0.0f;
        if (lane == 0) scf[WS_SC1 + r] = (m > 0.0f) ? m / 32767.0f : 0.0f;
        int w = lane;
        ws[WS_W1 + r * 64 + w] = pack16(q15(src[2 * w], inv), q15(src[2 * w + 1], inv));
    } else {                                          // vW0 row, 65 cols
        int r = row - kO - kW;
        const float* src = vW0 + (size_t)r * kIN;
        float m = fabsf(src[lane]);
        if (lane == 0) m = fmaxf(m, fabsf(src[64]));
        #pragma unroll
        for (int s = 1; s < 64; s <<= 1) m = fmaxf(m, __shfl_xor(m, s));
        float inv = (m > 0.0f) ? 32767.0f / m : 0.0f;
        if (lane == 0) scf[WS_SC0 + r] = (m > 0.0f) ? m / 32767.0f : 0.0f;
        if (lane < 33) {
            int c0 = 2 * lane, c1 = 2 * lane + 1;
            int qa = q15(src[c0], inv);
            int qb = (c1 < kIN) ? q15(src[c1], inv) : 0;
            ws[WS_W0 + r * 33 + lane] = pack16(qa, qb);
        }
    }
}

template <int QI>
__global__ __launch_bounds__(BLOCK)
void cde_kernel(
    const float* __restrict__ ts,  const float* __restrict__ ys,
    const float* __restrict__ iW0, const float* __restrict__ ib0,
    const float* __restrict__ iW1, const float* __restrict__ ib1,
    const float* __restrict__ iW2, const float* __restrict__ ib2,
    const float* __restrict__ vW0, const float* __restrict__ vb0,
    const float* __restrict__ vW1, const float* __restrict__ vb1,
    const float* __restrict__ vW2, const float* __restrict__ vb2,
    const float* __restrict__ rW,  const float* __restrict__ rb,
    const unsigned* __restrict__ wsb,
    float* __restrict__ out)
{
    const int b  = blockIdx.x;
    const int t  = threadIdx.x;
    const int r8 = t >> 3;     // 0..127
    const int g  = t & 7;      // 0..7
    const int wv = t >> 6;     // wave 0..15
    const int ln = t & 63;     // lane

    __shared__ __align__(16) float s_v[kO];
    __shared__ __align__(16) float s_z1[kW], s_z2[kW];
    __shared__ __align__(16) float s_inp[kIN + 1];   // [65] = 0 pad
    __shared__ float s_y[kH], s_yhat[kH], s_e[kH];
    __shared__ float s_dx[2][kC];                    // ping-pong

    const float*    ysb   = ys + (size_t)b * kT * kD;
    const uint4*    wsW2q = (const uint4*)(wsb + WS_W2);
    const unsigned* wsW1  = wsb + WS_W1;
    const unsigned* wsW0  = wsb + WS_W0;
    const float*    scf   = (const float*)wsb;

    const float bA  = vb2[t];
    const float bB  = vb2[t + 1024];
    const float bTl = (t < 512) ? vb2[2048 + r8] : 0.0f;
    const float b0r = vb0[r8];
    const float b1r = vb1[r8];
    const float sA  = QI ? scf[WS_SC2 + t] : 0.0f;
    const float sB  = QI ? scf[WS_SC2 + t + 1024] : 0.0f;
    const float sTl = (QI && t < 512) ? scf[WS_SC2 + 2048 + r8] : 0.0f;
    const float s0r = QI ? scf[WS_SC0 + r8] : 0.0f;
    const float s1r = QI ? scf[WS_SC1 + r8] : 0.0f;

    // ---- resident slice of row t: cols [0,112) = 14 uint4 (56 VGPRs)
    uint4 wreg[14];
    if (QI) {
        const uint4* pA0 = wsW2q + (size_t)(wv * 16) * 64 + ln;
        #pragma unroll
        for (int m = 0; m < 14; m++) wreg[m] = pA0[m * 64];
    }

    // ---- x0 + prefetch x1
    float x_reg = 0.0f, x_next = 0.0f;
    if (t < kC) {
        x_reg  = (t == 0) ? ts[0] : ysb[t - 1];
        x_next = (t == 0) ? ts[1] : ysb[kD + (t - 1)];
        s_dx[0][t] = x_reg;                 // temp staging for initial MLP
    }
    if (t == 0) s_inp[kIN] = 0.0f;          // pad
    __syncthreads();

    // ---- initial MLP (one-time, fp32)
    if (t < kW) {
        const float* wrow = iW0 + t * kC;
        float acc = ib0[t];
        #pragma unroll
        for (int c = 0; c < kC; c++) acc += wrow[c] * s_dx[0][c];
        s_z1[t] = fmaxf(acc, 0.0f);
    }
    __syncthreads();
    if (t < kW) {
        const float4* wr = (const float4*)(iW1 + t * kW);
        const float4* z4 = (const float4*)s_z1;
        float acc = ib1[t];
        #pragma unroll 8
        for (int q = 0; q < kW / 4; q++) acc += dot4(wr[q], z4[q]);
        s_z2[t] = fmaxf(acc, 0.0f);
    }
    __syncthreads();
    if (t < kH) {
        const float4* wr = (const float4*)(iW2 + t * kW);
        const float4* z4 = (const float4*)s_z2;
        float acc = ib2[t];
        #pragma unroll 8
        for (int q = 0; q < kW / 4; q++) acc += dot4(wr[q], z4[q]);
        s_y[t] = acc; s_yhat[t] = acc;
        s_inp[1 + t] = acc;
    }
    if (t == 0) s_inp[0] = x_reg;           // ts[0]
    __syncthreads();

    // ---- main scan
    for (int i = 0; i < kT; i++) {
        const int cur = i & 1;              // dx buffer for y-update (iter i)
        const int nxt = (i + 1) & 1;        // dx buffer phase A writes / phase B reads

        // ===== layer 1: 65->128, split-k-8, row r8 =====
        {
            float acc = 0.0f;
            if (QI) {
                const unsigned* rowp = wsW0 + r8 * 33;
                #pragma unroll
                for (int m = 0; m < 5; m++) {
                    int p = g + 8 * m;
                    if (p < 33) acc = fma2i(rowp[p], s_inp[2 * p], s_inp[2 * p + 1], acc);
                }
            } else {
                const float* rowp = vW0 + r8 * kIN;
                #pragma unroll
                for (int m = 0; m < 5; m++) {
                    int p = g + 8 * m;
                    if (p < 33) {
                        float w0 = rowp[2 * p];
                        float w1 = (2 * p + 1 < kIN) ? rowp[2 * p + 1] : 0.0f;
                        acc += w0 * s_inp[2 * p] + w1 * s_inp[2 * p + 1];
                    }
                }
            }
            acc += __shfl_xor(acc, 1);
            acc += __shfl_xor(acc, 2);
            acc += __shfl_xor(acc, 4);
            if (g == 0) s_z1[r8] = lipswish_f(b0r + (QI ? s0r * acc : acc));
        }
        __syncthreads();
        // ===== layer 2: 128->128, split-k-8, row r8 =====
        {
            float acc = 0.0f;
            #pragma unroll
            for (int m = 0; m < 2; m++) {
                int ch = g + 8 * m;
                int c0 = 8 * ch;
                const float4* z4 = (const float4*)(s_z1 + c0);
                float4 za = z4[0], zb = z4[1];
                if (QI) {
                    uint4 u = *(const uint4*)(wsW1 + r8 * 64 + 4 * ch);
                    acc = fma8i(u, za, zb, acc);
                } else {
                    const float* wr = vW1 + r8 * kW + c0;
                    acc += dot4(*(const float4*)wr, za) + dot4(*(const float4*)(wr + 4), zb);
                }
            }
            acc += __shfl_xor(acc, 1);
            acc += __shfl_xor(acc, 2);
            acc += __shfl_xor(acc, 4);
            if (g == 0) s_z2[r8] = lipswish_f(b1r + (QI ? s1r * acc : acc));
        }
        __syncthreads();
        // ===== layer 3 main: row t (cols 0..111 resident, rest streamed), row t+1024 streamed =====
        {
            float acc0 = 0.0f, acc1 = 0.0f;
            if (QI) {
                const uint4* pA = wsW2q + (size_t)(wv * 16) * 64 + ln;
                const uint4* pB = wsW2q + (size_t)((wv + 16) * 16) * 64 + ln;
                #pragma unroll
                for (int m = 0; m < 7; m++) {
                    const float4* z4 = (const float4*)(s_z2 + 16 * m);
                    float4 z0 = z4[0], z1 = z4[1], z2 = z4[2], z3 = z4[3];
                    uint4 c0 = pB[(2 * m) * 64], c1 = pB[(2 * m + 1) * 64];
                    acc0 = fma8i(wreg[2 * m], z0, z1, acc0);
                    acc0 = fma8i(wreg[2 * m + 1], z2, z3, acc0);
                    acc1 = fma8i(c0, z0, z1, acc1);
                    acc1 = fma8i(c1, z2, z3, acc1);
                }
                {   // m = 7: both rows streamed
                    const float4* z4 = (const float4*)(s_z2 + 112);
                    float4 z0 = z4[0], z1 = z4[1], z2 = z4[2], z3 = z4[3];
                    uint4 a0 = pA[14 * 64], a1 = pA[15 * 64];
                    uint4 c0 = pB[14 * 64], c1 = pB[15 * 64];
                    acc0 = fma8i(a0, z0, z1, acc0);
                    acc0 = fma8i(a1, z2, z3, acc0);
                    acc1 = fma8i(c0, z0, z1, acc1);
                    acc1 = fma8i(c1, z2, z3, acc1);
                }
                s_v[t]        = fast_tanh(bA + sA * acc0);
                s_v[t + 1024] = fast_tanh(bB + sB * acc1);
            } else {
                #pragma unroll 2
                for (int m = 0; m < 8; m++) {
                    const float4* z4 = (const float4*)(s_z2 + 16 * m);
                    float4 z0 = z4[0], z1 = z4[1], z2 = z4[2], z3 = z4[3];
                    const float4* rA = (const float4*)(vW2 + (size_t)t * kW + 16 * m);
                    const float4* rB = (const float4*)(vW2 + (size_t)(t + 1024) * kW + 16 * m);
                    acc0 += dot4(rA[0], z0) + dot4(rA[1], z1) + dot4(rA[2], z2) + dot4(rA[3], z3);
                    acc1 += dot4(rB[0], z0) + dot4(rB[1], z1) + dot4(rB[2], z2) + dot4(rB[3], z3);
                }
                s_v[t]        = fast_tanh(bA + acc0);
                s_v[t + 1024] = fast_tanh(bB + acc1);
            }
        }
        // ===== layer 3 tail: rows 2048..2111, split-k-8 =====
        if (t < 512) {
            int c0i = 16 * g;
            const float4* z4 = (const float4*)(s_z2 + c0i);
            float4 z0 = z4[0], z1 = z4[1], z2 = z4[2], z3 = z4[3];
            float acc = 0.0f;
            if (QI) {
                uint4 u0 = wsW2q[(size_t)(32 * 16 + 2 * g) * 64 + r8];
                uint4 u1 = wsW2q[(size_t)(32 * 16 + 2 * g + 1) * 64 + r8];
                acc = fma8i(u0, z0, z1, acc);
                acc = fma8i(u1, z2, z3, acc);
            } else {
                const float4* wr = (const float4*)(vW2 + (size_t)(2048 + r8) * kW + c0i);
                acc += dot4(wr[0], z0) + dot4(wr[1], z1) + dot4(wr[2], z2) + dot4(wr[3], z3);
            }
            acc += __shfl_xor(acc, 1);
            acc += __shfl_xor(acc, 2);
            acc += __shfl_xor(acc, 4);
            if (g == 0) s_v[2048 + r8] = fast_tanh(bTl + (QI ? sTl * acc : acc));
        }
        __syncthreads();

        // ===== merged region: y-update (reads dx[cur]) ∥ phase A (writes dx[nxt]) =====
        if (i > 0 && t < kH) {
            const float* vr = s_v + t * kC;
            float acc = 0.0f;
            #pragma unroll
            for (int c = 0; c < kC; c++) acc += vr[c] * s_dx[cur][c];
            s_y[t] += 0.5f * (s_e[t] + acc);
        }
        if (i < kT - 1 && t < kC) {
            float xi = x_next;
            s_dx[nxt][t] = xi - x_reg;
            x_reg = xi;
            if (i + 2 < kT)
                x_next = (t == 0) ? ts[i + 2] : ysb[(size_t)(i + 2) * kD + (t - 1)];
        }
        __syncthreads();

        // ===== phase B: e = v.dx[nxt] ; yhat update ; next vf input =====
        if (i < kT - 1) {
            if (t < kH) {
                const float* vr = s_v + t * kC;
                float e = 0.0f;
                #pragma unroll
                for (int c = 0; c < kC; c++) e += vr[c] * s_dx[nxt][c];
                s_e[t] = e;
                float yh = 2.0f * s_y[t] - s_yhat[t] + e;
                s_yhat[t] = yh;
                s_inp[1 + t] = yh;
            }
            if (t == 0) s_inp[0] = x_reg;   // = ts[i+1]
            __syncthreads();
        }
    }

    // ---- readout
    __syncthreads();
    if (t == 0) {
        float acc = rb[0];
        #pragma unroll
        for (int h = 0; h < kH; h++) acc += s_y[h] * rW[h];
        out[b] = acc;
    }
}

extern "C" void kernel_launch(void* const* d_in, const int* in_sizes, int n_in,
                              void* d_out, int out_size, void* d_ws, size_t ws_size,
                              hipStream_t stream)
{
    const float* ts  = (const float*)d_in[0];
    const float* ys  = (const float*)d_in[1];
    const float* iW0 = (const float*)d_in[2];
    const float* ib0 = (const float*)d_in[3];
    const float* iW1 = (const float*)d_in[4];
    const float* ib1 = (const float*)d_in[5];
    const float* iW2 = (const float*)d_in[6];
    const float* ib2 = (const float*)d_in[7];
    const float* vW0 = (const float*)d_in[8];
    const float* vb0 = (const float*)d_in[9];
    const float* vW1 = (const float*)d_in[10];
    const float* vb1 = (const float*)d_in[11];
    const float* vW2 = (const float*)d_in[12];
    const float* vb2 = (const float*)d_in[13];
    const float* rW  = (const float*)d_in[14];
    const float* rb  = (const float*)d_in[15];
    float* out = (float*)d_out;
    unsigned* ws = (unsigned*)d_ws;

    if (ws_size >= (size_t)WS_TOT * 4) {
        hipLaunchKernelGGL(prep_kernel, dim3(kO + kW + kW), dim3(64), 0, stream,
                           vW0, vW1, vW2, ws);
        hipLaunchKernelGGL((cde_kernel<1>), dim3(kB), dim3(BLOCK), 0, stream,
                           ts, ys, iW0, ib0, iW1, ib1, iW2, ib2,
                           vW0, vb0, vW1, vb1, vW2, vb2, rW, rb, ws, out);
    } else {
        hipLaunchKernelGGL((cde_kernel<0>), dim3(kB), dim3(BLOCK), 0, stream,
                           ts, ys, iW0, ib0, iW1, ib1, iW2, ib2,
                           vW0, vb0, vW1, vb1, vW2, vb2, rW, rb, ws, out);
    }
}

// Round 6
// 7431.525 us; speedup vs baseline: 6.6545x; 6.6545x over previous
//
#include <hip/hip_runtime.h>
#include <math.h>

constexpr int kB  = 128;
constexpr int kT  = 1024;
constexpr int kD  = 32;
constexpr int kH  = 64;
constexpr int kW  = 128;
constexpr int kC  = kD + 1;    // 33
constexpr int kO  = kH * kC;   // 2112
constexpr int kIN = kH + 1;    // 65
constexpr int BLOCK = 1024;    // 16 waves

// ---- workspace layout (u32 units) ----
// W2 main rows [0,2048): two byte-planes (hi, lo), tiled for coalescing:
//   uint4 index ((R*8+q)*64 + r), R=row>>6, r=row&63, q=0..7
// W2 tail rows [2048,2112): int16 pairs, uint4 index (q*64 + r), q=0..15, r=row-2048
constexpr int WS_W2H = 0;            // 65536 u32
constexpr int WS_W2L = 65536;        // 65536 u32
constexpr int WS_W2T = 131072;       // 4096 u32
constexpr int WS_W1  = 135168;       // 8192 u32  (128 rows * 64 words, row-major int16)
constexpr int WS_W0  = 143360;       // 4224 u32  (128 rows * 33 words int16)
constexpr int WS_SC2 = 147584;       // 2112 f32 row scales
constexpr int WS_SC1 = 149696;       // 128
constexpr int WS_SC0 = 149824;       // 128
constexpr int WS_TOT = 149952;       // 599,808 bytes

__device__ __forceinline__ float fast_sigmoid(float x) { return 1.0f / (1.0f + __expf(-x)); }
__device__ __forceinline__ float lipswish_f(float x)   { return 0.909f * x * fast_sigmoid(x); }
__device__ __forceinline__ float fast_tanh(float x) {
    float ax = fabsf(x);
    float e  = __expf(2.0f * ax);
    float r  = 1.0f - 2.0f / (e + 1.0f);
    return copysignf(r, x);
}
__device__ __forceinline__ float dot4(float4 a, float4 b) {
    return a.x * b.x + a.y * b.y + a.z * b.z + a.w * b.w;
}
__device__ __forceinline__ float fma2i(unsigned u, float z0, float z1, float acc) {
    int lo = (int)(short)(u & 0xffffu);
    int hi = ((int)u) >> 16;
    acc += (float)lo * z0 + (float)hi * z1;
    return acc;
}
__device__ __forceinline__ float fma8i(uint4 u, float4 zl, float4 zh, float acc) {
    acc = fma2i(u.x, zl.x, zl.y, acc);
    acc = fma2i(u.y, zl.z, zl.w, acc);
    acc = fma2i(u.z, zh.x, zh.y, acc);
    acc = fma2i(u.w, zh.z, zh.w, acc);
    return acc;
}
// signed 4x int8 dot product, exact
__device__ __forceinline__ int sdot4(int a, int b, int c) {
#if defined(__has_builtin)
#if __has_builtin(__builtin_amdgcn_sdot4)
    return __builtin_amdgcn_sdot4(a, b, c, false);
#else
    c += ((a << 24) >> 24) * ((b << 24) >> 24);
    c += ((a << 16) >> 24) * ((b << 16) >> 24);
    c += ((a <<  8) >> 24) * ((b <<  8) >> 24);
    c += (a >> 24) * (b >> 24);
    return c;
#endif
#else
    c += ((a << 24) >> 24) * ((b << 24) >> 24);
    c += ((a << 16) >> 24) * ((b << 16) >> 24);
    c += ((a <<  8) >> 24) * ((b <<  8) >> 24);
    c += (a >> 24) * (b >> 24);
    return c;
#endif
}
__device__ __forceinline__ int q15(float w, float inv) {
    float q = rintf(w * inv);
    q = fmaxf(-32767.0f, fminf(32767.0f, q));
    return (int)q;
}
__device__ __forceinline__ unsigned pack16(int a, int b) {
    return ((unsigned)a & 0xffffu) | ((unsigned)b << 16);
}
// quantize to +-32512, split into hi/lo signed bytes
__device__ __forceinline__ void qsplit(float w, float inv, int& h, int& l) {
    float qf = fminf(fmaxf(rintf(w * inv), -32512.0f), 32512.0f);
    int q = (int)qf;
    h = (q + 128) >> 8;         // [-127,127]
    l = q - (h << 8);           // [-128,127]
}

// one wave per row; rows: [0,2048) W2 main, [2048,2112) W2 tail, then W1, W0
__global__ __launch_bounds__(64)
void prep_kernel(const float* __restrict__ vW0, const float* __restrict__ vW1,
                 const float* __restrict__ vW2, unsigned* __restrict__ ws)
{
    const int row  = blockIdx.x;
    const int lane = threadIdx.x;
    float* scf = (float*)ws;

    if (row < 2048) {                                 // W2 main: byte planes
        const float* src = vW2 + (size_t)row * kW;
        float m = fmaxf(fabsf(src[lane]), fabsf(src[lane + 64]));
        #pragma unroll
        for (int s = 1; s < 64; s <<= 1) m = fmaxf(m, __shfl_xor(m, s));
        float inv = (m > 0.0f) ? 32512.0f / m : 0.0f;
        if (lane == 0) scf[WS_SC2 + row] = (m > 0.0f) ? m / 32512.0f : 0.0f;
        if (lane < 32) {
            int w = lane;                             // cols 4w..4w+3
            int h0, l0, h1, l1, h2, l2, h3, l3;
            qsplit(src[4 * w + 0], inv, h0, l0);
            qsplit(src[4 * w + 1], inv, h1, l1);
            qsplit(src[4 * w + 2], inv, h2, l2);
            qsplit(src[4 * w + 3], inv, h3, l3);
            unsigned uh = (unsigned)(h0 & 255) | ((unsigned)(h1 & 255) << 8) |
                          ((unsigned)(h2 & 255) << 16) | ((unsigned)(h3 & 255) << 24);
            unsigned ul = (unsigned)(l0 & 255) | ((unsigned)(l1 & 255) << 8) |
                          ((unsigned)(l2 & 255) << 16) | ((unsigned)(l3 & 255) << 24);
            int R = row >> 6, r = row & 63, q = w >> 2, e = w & 3;
            int idx = (((R * 8 + q) * 64 + r) << 2) + e;
            ws[WS_W2H + idx] = uh;
            ws[WS_W2L + idx] = ul;
        }
    } else if (row < kO) {                            // W2 tail: int16 tiles
        int r = row - 2048;
        const float* src = vW2 + (size_t)row * kW;
        float m = fmaxf(fabsf(src[lane]), fabsf(src[lane + 64]));
        #pragma unroll
        for (int s = 1; s < 64; s <<= 1) m = fmaxf(m, __shfl_xor(m, s));
        float inv = (m > 0.0f) ? 32767.0f / m : 0.0f;
        if (lane == 0) scf[WS_SC2 + row] = (m > 0.0f) ? m / 32767.0f : 0.0f;
        int w = lane;
        unsigned pk = pack16(q15(src[2 * w], inv), q15(src[2 * w + 1], inv));
        int q = w >> 2, e = w & 3;
        ws[WS_W2T + ((q * 64 + r) << 2) + e] = pk;
    } else if (row < kO + kW) {                       // W1 int16 row-major
        int r = row - kO;
        const float* src = vW1 + (size_t)r * kW;
        float m = fmaxf(fabsf(src[lane]), fabsf(src[lane + 64]));
        #pragma unroll
        for (int s = 1; s < 64; s <<= 1) m = fmaxf(m, __shfl_xor(m, s));
        float inv = (m > 0.0f) ? 32767.0f / m : 0.0f;
        if (lane == 0) scf[WS_SC1 + r] = (m > 0.0f) ? m / 32767.0f : 0.0f;
        ws[WS_W1 + r * 64 + lane] = pack16(q15(src[2 * lane], inv), q15(src[2 * lane + 1], inv));
    } else {                                          // W0 int16, 65 cols
        int r = row - kO - kW;
        const float* src = vW0 + (size_t)r * kIN;
        float m = fabsf(src[lane]);
        if (lane == 0) m = fmaxf(m, fabsf(src[64]));
        #pragma unroll
        for (int s = 1; s < 64; s <<= 1) m = fmaxf(m, __shfl_xor(m, s));
        float inv = (m > 0.0f) ? 32767.0f / m : 0.0f;
        if (lane == 0) scf[WS_SC0 + r] = (m > 0.0f) ? m / 32767.0f : 0.0f;
        if (lane < 33) {
            int c0 = 2 * lane, c1 = 2 * lane + 1;
            int qa = q15(src[c0], inv);
            int qb = (c1 < kIN) ? q15(src[c1], inv) : 0;
            ws[WS_W0 + r * 33 + lane] = pack16(qa, qb);
        }
    }
}

template <int QI>
__global__ __launch_bounds__(BLOCK)
__attribute__((amdgpu_waves_per_eu(4, 4)))
void cde_kernel(
    const float* __restrict__ ts,  const float* __restrict__ ys,
    const float* __restrict__ iW0, const float* __restrict__ ib0,
    const float* __restrict__ iW1, const float* __restrict__ ib1,
    const float* __restrict__ iW2, const float* __restrict__ ib2,
    const float* __restrict__ vW0, const float* __restrict__ vb0,
    const float* __restrict__ vW1, const float* __restrict__ vb1,
    const float* __restrict__ vW2, const float* __restrict__ vb2,
    const float* __restrict__ rW,  const float* __restrict__ rb,
    const unsigned* __restrict__ wsb,
    float* __restrict__ out)
{
    const int b  = blockIdx.x;
    const int t  = threadIdx.x;
    const int r8 = t >> 3;     // 0..127
    const int g  = t & 7;      // 0..7
    const int wv = t >> 6;     // wave 0..15
    const int ln = t & 63;     // lane

    __shared__ __align__(16) float s_v[kO];
    __shared__ __align__(16) float s_z1[kW], s_z2[kW];
    __shared__ __align__(16) float s_inp[kIN + 1];   // [65] = 0 pad
    __shared__ __align__(16) unsigned s_zqh[32], s_zql[32];
    __shared__ float s_y[kH], s_yhat[kH], s_e[kH];
    __shared__ float s_dx[2][kC];                    // ping-pong
    __shared__ int   s_maxi;
    __shared__ float s_zsc;

    const float*    ysb   = ys + (size_t)b * kT * kD;
    const uint4*    w2h   = (const uint4*)(wsb + WS_W2H);
    const uint4*    w2l   = (const uint4*)(wsb + WS_W2L);
    const uint4*    w2t   = (const uint4*)(wsb + WS_W2T);
    const unsigned* wsW1  = wsb + WS_W1;
    const unsigned* wsW0  = wsb + WS_W0;
    const float*    scf   = (const float*)wsb;

    const float bA  = vb2[t];
    const float bB  = vb2[t + 1024];
    const float bTl = (t < 512) ? vb2[2048 + r8] : 0.0f;
    const float b0r = vb0[r8];
    const float b1r = vb1[r8];
    const float sA  = QI ? scf[WS_SC2 + t] : 0.0f;
    const float sB  = QI ? scf[WS_SC2 + t + 1024] : 0.0f;
    const float sTl = (QI && t < 512) ? scf[WS_SC2 + 2048 + r8] : 0.0f;
    const float s0r = QI ? scf[WS_SC0 + r8] : 0.0f;
    const float s1r = QI ? scf[WS_SC1 + r8] : 0.0f;

    // ---- x0 + prefetch x1
    float x_reg = 0.0f, x_next = 0.0f;
    if (t < kC) {
        x_reg  = (t == 0) ? ts[0] : ysb[t - 1];
        x_next = (t == 0) ? ts[1] : ysb[kD + (t - 1)];
        s_dx[0][t] = x_reg;                 // temp staging for initial MLP
    }
    if (t == 0) s_inp[kIN] = 0.0f;          // pad
    __syncthreads();

    // ---- initial MLP (one-time, fp32)
    if (t < kW) {
        const float* wrow = iW0 + t * kC;
        float acc = ib0[t];
        #pragma unroll
        for (int c = 0; c < kC; c++) acc += wrow[c] * s_dx[0][c];
        s_z1[t] = fmaxf(acc, 0.0f);
    }
    __syncthreads();
    if (t < kW) {
        const float4* wr = (const float4*)(iW1 + t * kW);
        const float4* z4 = (const float4*)s_z1;
        float acc = ib1[t];
        #pragma unroll 8
        for (int q = 0; q < kW / 4; q++) acc += dot4(wr[q], z4[q]);
        s_z2[t] = fmaxf(acc, 0.0f);
    }
    __syncthreads();
    if (t < kH) {
        const float4* wr = (const float4*)(iW2 + t * kW);
        const float4* z4 = (const float4*)s_z2;
        float acc = ib2[t];
        #pragma unroll 8
        for (int q = 0; q < kW / 4; q++) acc += dot4(wr[q], z4[q]);
        s_y[t] = acc; s_yhat[t] = acc;
        s_inp[1 + t] = acc;
    }
    if (t == 0) s_inp[0] = x_reg;           // ts[0]
    __syncthreads();

    // ---- main scan
    for (int i = 0; i < kT; i++) {
        const int cur = i & 1;
        const int nxt = (i + 1) & 1;

        // ===== layer 1: 65->128, split-k-8, row r8 ===== (+ reset z2-max)
        if (t == 0) s_maxi = 0;
        {
            float acc = 0.0f;
            if (QI) {
                const unsigned* rowp = wsW0 + r8 * 33;
                #pragma unroll
                for (int m = 0; m < 5; m++) {
                    int p = g + 8 * m;
                    if (p < 33) acc = fma2i(rowp[p], s_inp[2 * p], s_inp[2 * p + 1], acc);
                }
            } else {
                const float* rowp = vW0 + r8 * kIN;
                #pragma unroll
                for (int m = 0; m < 5; m++) {
                    int p = g + 8 * m;
                    if (p < 33) {
                        float w0 = rowp[2 * p];
                        float w1 = (2 * p + 1 < kIN) ? rowp[2 * p + 1] : 0.0f;
                        acc += w0 * s_inp[2 * p] + w1 * s_inp[2 * p + 1];
                    }
                }
            }
            acc += __shfl_xor(acc, 1);
            acc += __shfl_xor(acc, 2);
            acc += __shfl_xor(acc, 4);
            if (g == 0) s_z1[r8] = lipswish_f(b0r + (QI ? s0r * acc : acc));
        }
        __syncthreads();
        // ===== layer 2: 128->128, split-k-8, row r8 ===== (+ |z2| max)
        {
            float acc = 0.0f;
            #pragma unroll
            for (int m = 0; m < 2; m++) {
                int ch = g + 8 * m;
                int c0 = 8 * ch;
                const float4* z4 = (const float4*)(s_z1 + c0);
                float4 za = z4[0], zb = z4[1];
                if (QI) {
                    uint4 u = *(const uint4*)(wsW1 + r8 * 64 + 4 * ch);
                    acc = fma8i(u, za, zb, acc);
                } else {
                    const float* wr = vW1 + r8 * kW + c0;
                    acc += dot4(*(const float4*)wr, za) + dot4(*(const float4*)(wr + 4), zb);
                }
            }
            acc += __shfl_xor(acc, 1);
            acc += __shfl_xor(acc, 2);
            acc += __shfl_xor(acc, 4);
            if (g == 0) {
                float zz = lipswish_f(b1r + (QI ? s1r * acc : acc));
                s_z2[r8] = zz;
                if (QI) atomicMax(&s_maxi, __float_as_int(fabsf(zz)));
            }
        }
        __syncthreads();
        // ===== phase: tail rows (waves 0-7, float z2) || z2 pack (wave 8) =====
        if (t < 512) {
            int c0i = 16 * g;
            const float4* z4 = (const float4*)(s_z2 + c0i);
            float4 z0 = z4[0], z1 = z4[1], z2 = z4[2], z3 = z4[3];
            float acc = 0.0f;
            if (QI) {
                uint4 u0 = w2t[(size_t)(2 * g) * 64 + r8];
                uint4 u1 = w2t[(size_t)(2 * g + 1) * 64 + r8];
                acc = fma8i(u0, z0, z1, acc);
                acc = fma8i(u1, z2, z3, acc);
            } else {
                const float4* wr = (const float4*)(vW2 + (size_t)(2048 + r8) * kW + c0i);
                acc += dot4(wr[0], z0) + dot4(wr[1], z1) + dot4(wr[2], z2) + dot4(wr[3], z3);
            }
            acc += __shfl_xor(acc, 1);
            acc += __shfl_xor(acc, 2);
            acc += __shfl_xor(acc, 4);
            if (g == 0) s_v[2048 + r8] = fast_tanh(bTl + (QI ? sTl * acc : acc));
        } else if (QI && t >= 512 && t < 544) {
            int p = t - 512;                          // 0..31
            float maxv = __int_as_float(s_maxi);
            float inv = (maxv > 0.0f) ? 32512.0f / maxv : 0.0f;
            if (p == 0) s_zsc = (maxv > 0.0f) ? maxv / 32512.0f : 0.0f;
            float4 z = ((const float4*)s_z2)[p];
            int h0, l0, h1, l1, h2, l2, h3, l3;
            qsplit(z.x, inv, h0, l0);
            qsplit(z.y, inv, h1, l1);
            qsplit(z.z, inv, h2, l2);
            qsplit(z.w, inv, h3, l3);
            s_zqh[p] = (unsigned)(h0 & 255) | ((unsigned)(h1 & 255) << 8) |
                       ((unsigned)(h2 & 255) << 16) | ((unsigned)(h3 & 255) << 24);
            s_zql[p] = (unsigned)(l0 & 255) | ((unsigned)(l1 & 255) << 8) |
                       ((unsigned)(l2 & 255) << 16) | ((unsigned)(l3 & 255) << 24);
        }
        __syncthreads();
        // ===== layer 3 main: rows t and t+1024, int8 composite sdot4 =====
        if (QI) {
            const uint4* pAH = w2h + (size_t)(wv * 8) * 64 + ln;
            const uint4* pAL = w2l + (size_t)(wv * 8) * 64 + ln;
            const uint4* pBH = w2h + (size_t)((wv + 16) * 8) * 64 + ln;
            const uint4* pBL = w2l + (size_t)((wv + 16) * 8) * 64 + ln;
            const uint4* zh4 = (const uint4*)s_zqh;
            const uint4* zl4 = (const uint4*)s_zql;
            int hhA = 0, hlA = 0, lhA = 0, llA = 0;
            int hhB = 0, hlB = 0, lhB = 0, llB = 0;
            #pragma unroll 4
            for (int q = 0; q < 8; q++) {
                uint4 zh = zh4[q], zl = zl4[q];
                uint4 ah = pAH[q * 64], al = pAL[q * 64];
                uint4 bh = pBH[q * 64], bl = pBL[q * 64];
                hhA = sdot4(ah.x, zh.x, hhA); hlA = sdot4(ah.x, zl.x, hlA);
                lhA = sdot4(al.x, zh.x, lhA); llA = sdot4(al.x, zl.x, llA);
                hhA = sdot4(ah.y, zh.y, hhA); hlA = sdot4(ah.y, zl.y, hlA);
                lhA = sdot4(al.y, zh.y, lhA); llA = sdot4(al.y, zl.y, llA);
                hhA = sdot4(ah.z, zh.z, hhA); hlA = sdot4(ah.z, zl.z, hlA);
                lhA = sdot4(al.z, zh.z, lhA); llA = sdot4(al.z, zl.z, llA);
                hhA = sdot4(ah.w, zh.w, hhA); hlA = sdot4(ah.w, zl.w, hlA);
                lhA = sdot4(al.w, zh.w, lhA); llA = sdot4(al.w, zl.w, llA);
                hhB = sdot4(bh.x, zh.x, hhB); hlB = sdot4(bh.x, zl.x, hlB);
                lhB = sdot4(bl.x, zh.x, lhB); llB = sdot4(bl.x, zl.x, llB);
                hhB = sdot4(bh.y, zh.y, hhB); hlB = sdot4(bh.y, zl.y, hlB);
                lhB = sdot4(bl.y, zh.y, lhB); llB = sdot4(bl.y, zl.y, llB);
                hhB = sdot4(bh.z, zh.z, hhB); hlB = sdot4(bh.z, zl.z, hlB);
                lhB = sdot4(bl.z, zh.z, lhB); llB = sdot4(bl.z, zl.z, llB);
                hhB = sdot4(bh.w, zh.w, hhB); hlB = sdot4(bh.w, zl.w, hlB);
                lhB = sdot4(bl.w, zh.w, lhB); llB = sdot4(bl.w, zl.w, llB);
            }
            float szf = s_zsc;
            float dA = 65536.0f * (float)hhA + 256.0f * (float)(hlA + lhA) + (float)llA;
            float dB = 65536.0f * (float)hhB + 256.0f * (float)(hlB + lhB) + (float)llB;
            s_v[t]        = fast_tanh(bA + sA * szf * dA);
            s_v[t + 1024] = fast_tanh(bB + sB * szf * dB);
        } else {
            float acc0 = 0.0f, acc1 = 0.0f;
            #pragma unroll 2
            for (int m = 0; m < 8; m++) {
                const float4* z4 = (const float4*)(s_z2 + 16 * m);
                float4 z0 = z4[0], z1 = z4[1], z2 = z4[2], z3 = z4[3];
                const float4* rA = (const float4*)(vW2 + (size_t)t * kW + 16 * m);
                const float4* rB = (const float4*)(vW2 + (size_t)(t + 1024) * kW + 16 * m);
                acc0 += dot4(rA[0], z0) + dot4(rA[1], z1) + dot4(rA[2], z2) + dot4(rA[3], z3);
                acc1 += dot4(rB[0], z0) + dot4(rB[1], z1) + dot4(rB[2], z2) + dot4(rB[3], z3);
            }
            s_v[t]        = fast_tanh(bA + acc0);
            s_v[t + 1024] = fast_tanh(bB + acc1);
        }
        __syncthreads();

        // ===== merged: y-update (reads dx[cur]) || phase A (writes dx[nxt]) =====
        if (i > 0 && t < kH) {
            const float* vr = s_v + t * kC;
            float acc = 0.0f;
            #pragma unroll
            for (int c = 0; c < kC; c++) acc += vr[c] * s_dx[cur][c];
            s_y[t] += 0.5f * (s_e[t] + acc);
        }
        if (i < kT - 1 && t < kC) {
            float xi = x_next;
            s_dx[nxt][t] = xi - x_reg;
            x_reg = xi;
            if (i + 2 < kT)
                x_next = (t == 0) ? ts[i + 2] : ysb[(size_t)(i + 2) * kD + (t - 1)];
        }
        __syncthreads();

        // ===== phase B: e = v.dx[nxt] ; yhat update ; next vf input =====
        if (i < kT - 1) {
            if (t < kH) {
                const float* vr = s_v + t * kC;
                float e = 0.0f;
                #pragma unroll
                for (int c = 0; c < kC; c++) e += vr[c] * s_dx[nxt][c];
                s_e[t] = e;
                float yh = 2.0f * s_y[t] - s_yhat[t] + e;
                s_yhat[t] = yh;
                s_inp[1 + t] = yh;
            }
            if (t == 0) s_inp[0] = x_reg;   // = ts[i+1]
            __syncthreads();
        }
    }

    // ---- readout
    __syncthreads();
    if (t == 0) {
        float acc = rb[0];
        #pragma unroll
        for (int h = 0; h < kH; h++) acc += s_y[h] * rW[h];
        out[b] = acc;
    }
}

extern "C" void kernel_launch(void* const* d_in, const int* in_sizes, int n_in,
                              void* d_out, int out_size, void* d_ws, size_t ws_size,
                              hipStream_t stream)
{
    const float* ts  = (const float*)d_in[0];
    const float* ys  = (const float*)d_in[1];
    const float* iW0 = (const float*)d_in[2];
    const float* ib0 = (const float*)d_in[3];
    const float* iW1 = (const float*)d_in[4];
    const float* ib1 = (const float*)d_in[5];
    const float* iW2 = (const float*)d_in[6];
    const float* ib2 = (const float*)d_in[7];
    const float* vW0 = (const float*)d_in[8];
    const float* vb0 = (const float*)d_in[9];
    const float* vW1 = (const float*)d_in[10];
    const float* vb1 = (const float*)d_in[11];
    const float* vW2 = (const float*)d_in[12];
    const float* vb2 = (const float*)d_in[13];
    const float* rW  = (const float*)d_in[14];
    const float* rb  = (const float*)d_in[15];
    float* out = (float*)d_out;
    unsigned* ws = (unsigned*)d_ws;

    if (ws_size >= (size_t)WS_TOT * 4) {
        hipLaunchKernelGGL(prep_kernel, dim3(kO + kW + kW), dim3(64), 0, stream,
                           vW0, vW1, vW2, ws);
        hipLaunchKernelGGL((cde_kernel<1>), dim3(kB), dim3(BLOCK), 0, stream,
                           ts, ys, iW0, ib0, iW1, ib1, iW2, ib2,
                           vW0, vb0, vW1, vb1, vW2, vb2, rW, rb, ws, out);
    } else {
        hipLaunchKernelGGL((cde_kernel<0>), dim3(kB), dim3(BLOCK), 0, stream,
                           ts, ys, iW0, ib0, iW1, ib1, iW2, ib2,
                           vW0, vb0, vW1, vb1, vW2, vb2, rW, rb, ws, out);
    }
}

// Round 7
// 7408.862 us; speedup vs baseline: 6.6749x; 1.0031x over previous
//
#include <hip/hip_runtime.h>
#include <math.h>

constexpr int kB  = 128;
constexpr int kT  = 1024;
constexpr int kD  = 32;
constexpr int kH  = 64;
constexpr int kW  = 128;
constexpr int kC  = kD + 1;    // 33
constexpr int kO  = kH * kC;   // 2112
constexpr int kIN = kH + 1;    // 65
constexpr int BLOCK = 1024;    // 16 waves

// ---- int16 workspace layout (u32 units) ----
// W2: transposed tiles: uint4 index (R*16+q)*64 + r ; R=row>>6, r=row&63, q=0..15
constexpr int WS_W2  = 0;            // 135168 u32 (2112 rows * 64 words)
constexpr int WS_W1  = 135168;       // 8192 u32  (128 rows * 64 words, row-major)
constexpr int WS_W0  = 143360;       // 4224 u32  (128 rows * 33 words, 65 cols + pad)
constexpr int WS_SC2 = 147584;       // 2112 f32 row scales
constexpr int WS_SC1 = 149696;       // 128
constexpr int WS_SC0 = 149824;       // 128
constexpr int WS_BAR = 149952;       // 8 u32 pacing counters (one per blockIdx&7 group)
constexpr int WS_TOT = 149960;       // u32 -> 599,840 bytes

__device__ __forceinline__ float fast_sigmoid(float x) { return 1.0f / (1.0f + __expf(-x)); }
__device__ __forceinline__ float lipswish_f(float x)   { return 0.909f * x * fast_sigmoid(x); }
__device__ __forceinline__ float fast_tanh(float x) {
    float ax = fabsf(x);
    float e  = __expf(2.0f * ax);
    float r  = 1.0f - 2.0f / (e + 1.0f);
    return copysignf(r, x);
}
__device__ __forceinline__ float dot4(float4 a, float4 b) {
    return a.x * b.x + a.y * b.y + a.z * b.z + a.w * b.w;
}
// acc += dot(int16 pair in u, z0, z1)
__device__ __forceinline__ float fma2i(unsigned u, float z0, float z1, float acc) {
    int lo = (int)(short)(u & 0xffffu);
    int hi = ((int)u) >> 16;
    acc += (float)lo * z0 + (float)hi * z1;
    return acc;
}
__device__ __forceinline__ float fma8i(uint4 u, float4 zl, float4 zh, float acc) {
    acc = fma2i(u.x, zl.x, zl.y, acc);
    acc = fma2i(u.y, zl.z, zl.w, acc);
    acc = fma2i(u.z, zh.x, zh.y, acc);
    acc = fma2i(u.w, zh.z, zh.w, acc);
    return acc;
}
__device__ __forceinline__ int q15(float w, float inv) {
    float q = rintf(w * inv);
    q = fmaxf(-32767.0f, fminf(32767.0f, q));
    return (int)q;
}
__device__ __forceinline__ unsigned pack16(int a, int b) {
    return ((unsigned)a & 0xffffu) | ((unsigned)b << 16);
}

// one wave (64 threads) per row; rows: [0,2112) W2, [2112,2240) W1, [2240,2368) W0
__global__ __launch_bounds__(64)
void prep_kernel(const float* __restrict__ vW0, const float* __restrict__ vW1,
                 const float* __restrict__ vW2, unsigned* __restrict__ ws)
{
    const int row  = blockIdx.x;
    const int lane = threadIdx.x;
    float* scf = (float*)ws;

    if (row == 0 && lane < 8) ws[WS_BAR + lane] = 0;   // zero pacing counters

    if (row < kO) {                                   // vW2 row, 128 cols
        const float* src = vW2 + (size_t)row * kW;
        float m = fmaxf(fabsf(src[lane]), fabsf(src[lane + 64]));
        #pragma unroll
        for (int s = 1; s < 64; s <<= 1) m = fmaxf(m, __shfl_xor(m, s));
        float inv = (m > 0.0f) ? 32767.0f / m : 0.0f;
        if (lane == 0) scf[WS_SC2 + row] = (m > 0.0f) ? m / 32767.0f : 0.0f;
        int w = lane;
        unsigned pk = pack16(q15(src[2 * w], inv), q15(src[2 * w + 1], inv));
        int R = row >> 6, r = row & 63, q = w >> 2, e = w & 3;
        ws[WS_W2 + (((R * 16 + q) * 64 + r) << 2) + e] = pk;
    } else if (row < kO + kW) {                       // vW1 row, 128 cols
        int r = row - kO;
        const float* src = vW1 + (size_t)r * kW;
        float m = fmaxf(fabsf(src[lane]), fabsf(src[lane + 64]));
        #pragma unroll
        for (int s = 1; s < 64; s <<= 1) m = fmaxf(m, __shfl_xor(m, s));
        float inv = (m > 0.0f) ? 32767.0f / m : 0.0f;
        if (lane == 0) scf[WS_SC1 + r] = (m > 0.0f) ? m / 32767.0f : 0.0f;
        int w = lane;
        ws[WS_W1 + r * 64 + w] = pack16(q15(src[2 * w], inv), q15(src[2 * w + 1], inv));
    } else {                                          // vW0 row, 65 cols
        int r = row - kO - kW;
        const float* src = vW0 + (size_t)r * kIN;
        float m = fabsf(src[lane]);
        if (lane == 0) m = fmaxf(m, fabsf(src[64]));
        #pragma unroll
        for (int s = 1; s < 64; s <<= 1) m = fmaxf(m, __shfl_xor(m, s));
        float inv = (m > 0.0f) ? 32767.0f / m : 0.0f;
        if (lane == 0) scf[WS_SC0 + r] = (m > 0.0f) ? m / 32767.0f : 0.0f;
        if (lane < 33) {
            int c0 = 2 * lane, c1 = 2 * lane + 1;
            int qa = q15(src[c0], inv);
            int qb = (c1 < kIN) ? q15(src[c1], inv) : 0;
            ws[WS_W0 + r * 33 + lane] = pack16(qa, qb);
        }
    }
}

template <int QI>
__global__ __launch_bounds__(BLOCK)
void cde_kernel(
    const float* __restrict__ ts,  const float* __restrict__ ys,
    const float* __restrict__ iW0, const float* __restrict__ ib0,
    const float* __restrict__ iW1, const float* __restrict__ ib1,
    const float* __restrict__ iW2, const float* __restrict__ ib2,
    const float* __restrict__ vW0, const float* __restrict__ vb0,
    const float* __restrict__ vW1, const float* __restrict__ vb1,
    const float* __restrict__ vW2, const float* __restrict__ vb2,
    const float* __restrict__ rW,  const float* __restrict__ rb,
    const unsigned* __restrict__ wsb,
    float* __restrict__ out)
{
    const int b  = blockIdx.x;
    const int t  = threadIdx.x;
    const int r8 = t >> 3;     // 0..127
    const int g  = t & 7;      // 0..7
    const int wv = t >> 6;     // wave 0..15
    const int ln = t & 63;     // lane
    const int grp = b & 7;     // XCD group (round-robin dispatch heuristic)

    __shared__ __align__(16) float s_v[kO];
    __shared__ __align__(16) float s_z1[kW], s_z2[kW];
    __shared__ __align__(16) float s_inp[kIN + 1];   // [65] = 0 pad
    __shared__ float s_y[kH], s_yhat[kH], s_e[kH];
    __shared__ float s_dx[2][kC];                    // ping-pong

    const float*    ysb   = ys + (size_t)b * kT * kD;
    const uint4*    wsW2q = (const uint4*)(wsb + WS_W2);
    const unsigned* wsW1  = wsb + WS_W1;
    const unsigned* wsW0  = wsb + WS_W0;
    const float*    scf   = (const float*)wsb;
    unsigned*       bar   = (unsigned*)(wsb + WS_BAR);   // pacing only — never affects results

    const float bA  = vb2[t];
    const float bB  = vb2[t + 1024];
    const float bTl = (t < 512) ? vb2[2048 + r8] : 0.0f;
    const float b0r = vb0[r8];
    const float b1r = vb1[r8];
    const float sA  = QI ? scf[WS_SC2 + t] : 0.0f;
    const float sB  = QI ? scf[WS_SC2 + t + 1024] : 0.0f;
    const float sTl = (QI && t < 512) ? scf[WS_SC2 + 2048 + r8] : 0.0f;
    const float s0r = QI ? scf[WS_SC0 + r8] : 0.0f;
    const float s1r = QI ? scf[WS_SC1 + r8] : 0.0f;

    // ---- x0 + prefetch x1
    float x_reg = 0.0f, x_next = 0.0f;
    if (t < kC) {
        x_reg  = (t == 0) ? ts[0] : ysb[t - 1];
        x_next = (t == 0) ? ts[1] : ysb[kD + (t - 1)];
        s_dx[0][t] = x_reg;                 // temp staging for initial MLP
    }
    if (t == 0) s_inp[kIN] = 0.0f;          // pad
    __syncthreads();

    // ---- initial MLP (one-time, fp32)
    if (t < kW) {
        const float* wrow = iW0 + t * kC;
        float acc = ib0[t];
        #pragma unroll
        for (int c = 0; c < kC; c++) acc += wrow[c] * s_dx[0][c];
        s_z1[t] = fmaxf(acc, 0.0f);
    }
    __syncthreads();
    if (t < kW) {
        const float4* wr = (const float4*)(iW1 + t * kW);
        const float4* z4 = (const float4*)s_z1;
        float acc = ib1[t];
        #pragma unroll 8
        for (int q = 0; q < kW / 4; q++) acc += dot4(wr[q], z4[q]);
        s_z2[t] = fmaxf(acc, 0.0f);
    }
    __syncthreads();
    if (t < kH) {
        const float4* wr = (const float4*)(iW2 + t * kW);
        const float4* z4 = (const float4*)s_z2;
        float acc = ib2[t];
        #pragma unroll 8
        for (int q = 0; q < kW / 4; q++) acc += dot4(wr[q], z4[q]);
        s_y[t] = acc; s_yhat[t] = acc;
        s_inp[1 + t] = acc;
    }
    if (t == 0) s_inp[0] = x_reg;           // ts[0]
    __syncthreads();

    // ---- main scan
    for (int i = 0; i < kT; i++) {
        const int cur = i & 1;              // dx buffer for y-update (iter i)
        const int nxt = (i + 1) & 1;        // dx buffer phase A writes / phase B reads

        // ===== pacing barrier: wait until all 16 group members finished step i-1's
        // weight reads. PERF ONLY (bounded spin, correctness never depends on it).
        if (QI) {
            if (t == 0 && i > 0) {
                unsigned tgt = (unsigned)(16 * i);
                int guard = 0;
                while (__hip_atomic_load(bar + grp, __ATOMIC_RELAXED,
                                         __HIP_MEMORY_SCOPE_AGENT) < tgt &&
                       ++guard < 4000)
                    __builtin_amdgcn_s_sleep(2);
            }
            __syncthreads();
        }

        // ===== layer 1: 65->128, split-k-8, row r8 =====
        {
            float acc = 0.0f;
            if (QI) {
                const unsigned* rowp = wsW0 + r8 * 33;
                #pragma unroll
                for (int m = 0; m < 5; m++) {
                    int p = g + 8 * m;
                    if (p < 33) acc = fma2i(rowp[p], s_inp[2 * p], s_inp[2 * p + 1], acc);
                }
            } else {
                const float* rowp = vW0 + r8 * kIN;
                #pragma unroll
                for (int m = 0; m < 5; m++) {
                    int p = g + 8 * m;
                    if (p < 33) {
                        float w0 = rowp[2 * p];
                        float w1 = (2 * p + 1 < kIN) ? rowp[2 * p + 1] : 0.0f;
                        acc += w0 * s_inp[2 * p] + w1 * s_inp[2 * p + 1];
                    }
                }
            }
            acc += __shfl_xor(acc, 1);
            acc += __shfl_xor(acc, 2);
            acc += __shfl_xor(acc, 4);
            if (g == 0) s_z1[r8] = lipswish_f(b0r + (QI ? s0r * acc : acc));
        }
        __syncthreads();
        // ===== layer 2: 128->128, split-k-8, row r8 =====
        {
            float acc = 0.0f;
            #pragma unroll
            for (int m = 0; m < 2; m++) {
                int ch = g + 8 * m;
                int c0 = 8 * ch;
                const float4* z4 = (const float4*)(s_z1 + c0);
                float4 za = z4[0], zb = z4[1];
                if (QI) {
                    uint4 u = *(const uint4*)(wsW1 + r8 * 64 + 4 * ch);
                    acc = fma8i(u, za, zb, acc);
                } else {
                    const float* wr = vW1 + r8 * kW + c0;
                    acc += dot4(*(const float4*)wr, za) + dot4(*(const float4*)(wr + 4), zb);
                }
            }
            acc += __shfl_xor(acc, 1);
            acc += __shfl_xor(acc, 2);
            acc += __shfl_xor(acc, 4);
            if (g == 0) s_z2[r8] = lipswish_f(b1r + (QI ? s1r * acc : acc));
        }
        __syncthreads();
        // ===== layer 3 main: rows t and t+1024, streamed (phase-locked -> L2-hit) =====
        {
            float acc0 = 0.0f, acc1 = 0.0f;
            if (QI) {
                const uint4* pA = wsW2q + (size_t)(wv * 16) * 64 + ln;
                const uint4* pB = wsW2q + (size_t)((wv + 16) * 16) * 64 + ln;
                #pragma unroll 2
                for (int m = 0; m < 8; m++) {
                    const float4* z4 = (const float4*)(s_z2 + 16 * m);
                    float4 z0 = z4[0], z1 = z4[1], z2 = z4[2], z3 = z4[3];
                    uint4 a0 = pA[(2 * m) * 64], a1 = pA[(2 * m + 1) * 64];
                    uint4 c0 = pB[(2 * m) * 64], c1 = pB[(2 * m + 1) * 64];
                    acc0 = fma8i(a0, z0, z1, acc0);
                    acc0 = fma8i(a1, z2, z3, acc0);
                    acc1 = fma8i(c0, z0, z1, acc1);
                    acc1 = fma8i(c1, z2, z3, acc1);
                }
                s_v[t]        = fast_tanh(bA + sA * acc0);
                s_v[t + 1024] = fast_tanh(bB + sB * acc1);
            } else {
                #pragma unroll 2
                for (int m = 0; m < 8; m++) {
                    const float4* z4 = (const float4*)(s_z2 + 16 * m);
                    float4 z0 = z4[0], z1 = z4[1], z2 = z4[2], z3 = z4[3];
                    const float4* rA = (const float4*)(vW2 + (size_t)t * kW + 16 * m);
                    const float4* rB = (const float4*)(vW2 + (size_t)(t + 1024) * kW + 16 * m);
                    acc0 += dot4(rA[0], z0) + dot4(rA[1], z1) + dot4(rA[2], z2) + dot4(rA[3], z3);
                    acc1 += dot4(rB[0], z0) + dot4(rB[1], z1) + dot4(rB[2], z2) + dot4(rB[3], z3);
                }
                s_v[t]        = fast_tanh(bA + acc0);
                s_v[t + 1024] = fast_tanh(bB + acc1);
            }
        }
        // ===== layer 3 tail: rows 2048..2111, split-k-8 =====
        if (t < 512) {
            int c0i = 16 * g;
            const float4* z4 = (const float4*)(s_z2 + c0i);
            float4 z0 = z4[0], z1 = z4[1], z2 = z4[2], z3 = z4[3];
            float acc = 0.0f;
            if (QI) {
                uint4 u0 = wsW2q[(size_t)(32 * 16 + 2 * g) * 64 + r8];
                uint4 u1 = wsW2q[(size_t)(32 * 16 + 2 * g + 1) * 64 + r8];
                acc = fma8i(u0, z0, z1, acc);
                acc = fma8i(u1, z2, z3, acc);
            } else {
                const float4* wr = (const float4*)(vW2 + (size_t)(2048 + r8) * kW + c0i);
                acc += dot4(wr[0], z0) + dot4(wr[1], z1) + dot4(wr[2], z2) + dot4(wr[3], z3);
            }
            acc += __shfl_xor(acc, 1);
            acc += __shfl_xor(acc, 2);
            acc += __shfl_xor(acc, 4);
            if (g == 0) s_v[2048 + r8] = fast_tanh(bTl + (QI ? sTl * acc : acc));
        }
        __syncthreads();

        // ===== pacing barrier arrive: this block's step-i weight reads are done =====
        if (QI && t == 0) atomicAdd(bar + grp, 1u);

        // ===== merged: y-update (reads dx[cur]) || phase A (writes dx[nxt]) =====
        if (i > 0 && t < kH) {
            const float* vr = s_v + t * kC;
            float acc = 0.0f;
            #pragma unroll
            for (int c = 0; c < kC; c++) acc += vr[c] * s_dx[cur][c];
            s_y[t] += 0.5f * (s_e[t] + acc);
        }
        if (i < kT - 1 && t < kC) {
            float xi = x_next;
            s_dx[nxt][t] = xi - x_reg;
            x_reg = xi;
            if (i + 2 < kT)
                x_next = (t == 0) ? ts[i + 2] : ysb[(size_t)(i + 2) * kD + (t - 1)];
        }
        __syncthreads();

        // ===== phase B: e = v.dx[nxt] ; yhat update ; next vf input =====
        if (i < kT - 1) {
            if (t < kH) {
                const float* vr = s_v + t * kC;
                float e = 0.0f;
                #pragma unroll
                for (int c = 0; c < kC; c++) e += vr[c] * s_dx[nxt][c];
                s_e[t] = e;
                float yh = 2.0f * s_y[t] - s_yhat[t] + e;
                s_yhat[t] = yh;
                s_inp[1 + t] = yh;
            }
            if (t == 0) s_inp[0] = x_reg;   // = ts[i+1]
            __syncthreads();
        }
    }

    // ---- readout
    __syncthreads();
    if (t == 0) {
        float acc = rb[0];
        #pragma unroll
        for (int h = 0; h < kH; h++) acc += s_y[h] * rW[h];
        out[b] = acc;
    }
}

extern "C" void kernel_launch(void* const* d_in, const int* in_sizes, int n_in,
                              void* d_out, int out_size, void* d_ws, size_t ws_size,
                              hipStream_t stream)
{
    const float* ts  = (const float*)d_in[0];
    const float* ys  = (const float*)d_in[1];
    const float* iW0 = (const float*)d_in[2];
    const float* ib0 = (const float*)d_in[3];
    const float* iW1 = (const float*)d_in[4];
    const float* ib1 = (const float*)d_in[5];
    const float* iW2 = (const float*)d_in[6];
    const float* ib2 = (const float*)d_in[7];
    const float* vW0 = (const float*)d_in[8];
    const float* vb0 = (const float*)d_in[9];
    const float* vW1 = (const float*)d_in[10];
    const float* vb1 = (const float*)d_in[11];
    const float* vW2 = (const float*)d_in[12];
    const float* vb2 = (const float*)d_in[13];
    const float* rW  = (const float*)d_in[14];
    const float* rb  = (const float*)d_in[15];
    float* out = (float*)d_out;
    unsigned* ws = (unsigned*)d_ws;

    if (ws_size >= (size_t)WS_TOT * 4) {
        hipLaunchKernelGGL(prep_kernel, dim3(kO + kW + kW), dim3(64), 0, stream,
                           vW0, vW1, vW2, ws);
        hipLaunchKernelGGL((cde_kernel<1>), dim3(kB), dim3(BLOCK), 0, stream,
                           ts, ys, iW0, ib0, iW1, ib1, iW2, ib2,
                           vW0, vb0, vW1, vb1, vW2, vb2, rW, rb, ws, out);
    } else {
        hipLaunchKernelGGL((cde_kernel<0>), dim3(kB), dim3(BLOCK), 0, stream,
                           ts, ys, iW0, ib0, iW1, ib1, iW2, ib2,
                           vW0, vb0, vW1, vb1, vW2, vb2, rW, rb, ws, out);
    }
}